// Round 1
// 86.408 us; speedup vs baseline: 1.1192x; 1.1192x over previous
//
#include <hip/hip_runtime.h>

#define BB 4
#define NN 4096

typedef __attribute__((ext_vector_type(8))) short short8v;   // 8 bf16 = 4 VGPRs
typedef __attribute__((ext_vector_type(4))) short short4v;   // 4 bf16 = 2 VGPRs
typedef __attribute__((ext_vector_type(4))) float float4v;
typedef __attribute__((ext_vector_type(16))) float f32x16;   // 32x32 MFMA acc

__device__ __forceinline__ unsigned short f2bf_rn(float f) {
    unsigned u = __float_as_uint(f);
    u += 0x7FFFu + ((u >> 16) & 1u);          // round-to-nearest-even
    return (unsigned short)(u >> 16);
}

// ---------------------------------------------------------------------------
// Kernel 1: fused QKV projection as an MFMA GEMM (unchanged structure).
// Outputs:
//   Qt[b][n][8], Kt[b][n][8]  (contiguous 16B rows)
//   Vsw: V pre-swizzled into 32x32x16 MFMA A-fragment order: 1 KB chunk per
//   (b, ct in [0,2), ns = n/16): elem[l*8+j] = V[b][ct*32+(l&31)][ns*16+(l>>5)*8+j]
//   so attn's V load is base + lane*16B — fully coalesced.
// ---------------------------------------------------------------------------
__global__ __launch_bounds__(256) void qkv_kernel(
    const float* __restrict__ x,
    const float* __restrict__ Wq, const float* __restrict__ Wk,
    const float* __restrict__ Wv,
    unsigned short* __restrict__ Qt, unsigned short* __restrict__ Kt,
    unsigned short* __restrict__ Vsw)
{
    __shared__ __align__(16) unsigned short xs[64][68];   // [c][n] bf16
    __shared__ __align__(16) unsigned short Ot[64][72];   // [c][n] V staging (144B rows)

    const int t    = threadIdx.x;
    const int w    = t >> 6;
    const int lane = t & 63;
    const int quad = lane >> 4;
    const int l15  = lane & 15;
    const int b    = blockIdx.y;
    const int n0   = blockIdx.x * 64;

    // ---- stage x tile (fp32 -> bf16)
    #pragma unroll
    for (int i = 0; i < 4; ++i) {
        int c  = (t >> 4) + i * 16;
        int n4 = (t & 15) * 4;
        float4 xv = *(const float4*)&x[(size_t)(b * 64 + c) * NN + n0 + n4];
        short4v pk;
        pk[0] = (short)f2bf_rn(xv.x); pk[1] = (short)f2bf_rn(xv.y);
        pk[2] = (short)f2bf_rn(xv.z); pk[3] = (short)f2bf_rn(xv.w);
        *(short4v*)&xs[c][n4] = pk;
    }

    // ---- W B-fragments: B[k=c][o=l15]
    short8v bw[5][2];
    #pragma unroll
    for (int ot = 0; ot < 5; ++ot) {
        int o = ot * 16 + l15;
        const float* base = (o < 8)  ? (Wq + o * 64)
                           : (o < 16) ? (Wk + (o - 8) * 64)
                                      : (Wv + (o - 16) * 64);
        #pragma unroll
        for (int h = 0; h < 2; ++h) {
            float4 u0 = *(const float4*)&base[h * 32 + quad * 8];
            float4 u1 = *(const float4*)&base[h * 32 + quad * 8 + 4];
            short8v f;
            f[0] = (short)f2bf_rn(u0.x); f[1] = (short)f2bf_rn(u0.y);
            f[2] = (short)f2bf_rn(u0.z); f[3] = (short)f2bf_rn(u0.w);
            f[4] = (short)f2bf_rn(u1.x); f[5] = (short)f2bf_rn(u1.y);
            f[6] = (short)f2bf_rn(u1.z); f[7] = (short)f2bf_rn(u1.w);
            bw[ot][h] = f;
        }
    }
    __syncthreads();

    // ---- A-fragments: A[m=n][k=c] from xs
    short8v a0, a1;
    {
        unsigned short* p0 = (unsigned short*)&a0;
        unsigned short* p1 = (unsigned short*)&a1;
        const int nn = w * 16 + l15;
        #pragma unroll
        for (int j = 0; j < 8; ++j) {
            p0[j] = xs[quad * 8 + j][nn];
            p1[j] = xs[32 + quad * 8 + j][nn];
        }
    }

    const float4v zacc = {0.f, 0.f, 0.f, 0.f};
    #pragma unroll
    for (int ot = 0; ot < 5; ++ot) {
        float4v d = __builtin_amdgcn_mfma_f32_16x16x32_bf16(a0, bw[ot][0], zacc, 0, 0, 0);
        d = __builtin_amdgcn_mfma_f32_16x16x32_bf16(a1, bw[ot][1], d, 0, 0, 0);
        if (ot == 0) {
            #pragma unroll
            for (int r = 0; r < 4; ++r) {
                unsigned short v = f2bf_rn(d[r]);
                size_t n = (size_t)(n0 + w * 16 + quad * 4 + r);
                if (l15 < 8) Qt[((size_t)b * NN + n) * 8 + l15] = v;
                else         Kt[((size_t)b * NN + n) * 8 + (l15 - 8)] = v;
            }
        } else {
            short4v pk;
            #pragma unroll
            for (int r = 0; r < 4; ++r) pk[r] = (short)f2bf_rn(d[r]);
            *(short4v*)&Ot[(ot - 1) * 16 + l15][w * 16 + quad * 4] = pk;
        }
    }
    __syncthreads();

    // ---- swizzled V writer for 32x32x16 A-fragments:
    // 8 chunks of 1 KB per block: (ct in [0,2)) x (nsl in [0,4)); wave w writes
    // chunks w*2 and w*2+1, each as one fully-coalesced 1 KB store.
    #pragma unroll
    for (int h = 0; h < 2; ++h) {
        int ci  = w * 2 + h;
        int ct  = ci >> 2, nsl = ci & 3;
        short8v d = *(const short8v*)&Ot[ct * 32 + (lane & 31)][nsl * 16 + ((lane >> 5) << 3)];
        size_t ns = (size_t)blockIdx.x * 4 + nsl;
        unsigned short* cb = Vsw + (((size_t)b * 2 + ct) * 256 + ns) * 512;
        *(short8v*)(cb + lane * 8) = d;
    }
}

// ---------------------------------------------------------------------------
// Kernel 2: streaming attention, 32x32x16 MFMA, fully in-register softmax.
// Block = 8 waves (512 thr); block owns (b, 32-wide m-tile). Wave w owns
// n in [w*512, (w+1)*512), 16 iters of 32 n. Main loop has ZERO LDS traffic:
// the P (exp(scores)) D-layout -> B-operand transpose is done with
// 8x v_cvt_pk_bf16_f32 + 4x v_permlane32_swap_b32 (T12).
//   D layout (32x32): col=lane&31, row=(reg&3)+8*(reg>>2)+4*(lane>>5)
//   B layout:         col=lane&31, k  =(lane>>5)*8+j
//   => swap(x2,x0) yields {W2,W0}; x_t = cvt_pk of d[2t],d[2t+1].
// ---------------------------------------------------------------------------
__global__ __launch_bounds__(512, 4) void attn_kernel(
    const unsigned short* __restrict__ Qt,
    const unsigned short* __restrict__ Kt,
    const unsigned short* __restrict__ Vsw,
    const float* __restrict__ x, const float* __restrict__ gamma,
    float* __restrict__ out)
{
    __shared__ __align__(16) float Ored[4][64][36];   // 36.9 KB
    __shared__ __align__(16) float Lred[8][32];
    __shared__ __align__(16) float Lf[32];

    const int t    = threadIdx.x;
    const int w    = t >> 6;
    const int lane = t & 63;
    const int hi   = lane >> 5;
    const int l31  = lane & 31;
    const int b    = blockIdx.y;
    const int m0   = blockIdx.x * 32;

    const short8v zfrag = {0, 0, 0, 0, 0, 0, 0, 0};
    const f32x16 zero16 = {0.f, 0.f, 0.f, 0.f, 0.f, 0.f, 0.f, 0.f,
                           0.f, 0.f, 0.f, 0.f, 0.f, 0.f, 0.f, 0.f};

    // K-side (query-column) B fragment: k=c=(hi*8+j); only c<8 real -> lo half
    short8v bk = zfrag;
    if (!hi) bk = *(const short8v*)(Kt + ((size_t)b * NN + m0 + l31) * 8);

    f32x16 acc0 = zero16, acc1 = zero16;
    float Lacc = 0.f;

    const unsigned short* qp  = Qt + ((size_t)b * NN + w * 512) * 8;
    const unsigned short* v0p = Vsw + ((size_t)b * 2 * 256 + w * 32) * 512 + lane * 8;
    const unsigned short* v1p = v0p + 256 * 512;

    // ---- prefetch iter 0 (all coalesced)
    short8v aqn = zfrag;
    if (!hi) aqn = *(const short8v*)(qp + (size_t)l31 * 8);
    short8v a00n = *(const short8v*)(v0p);
    short8v a01n = *(const short8v*)(v0p + 512);
    short8v a10n = *(const short8v*)(v1p);
    short8v a11n = *(const short8v*)(v1p + 512);

    for (int it = 0; it < 16; ++it) {
        short8v aq  = aqn;
        short8v a00 = a00n, a01 = a01n, a10 = a10n, a11 = a11n;

        const int itn = (it + 1) & 15;
        a00n = *(const short8v*)(v0p + itn * 1024);
        a01n = *(const short8v*)(v0p + itn * 1024 + 512);
        a10n = *(const short8v*)(v1p + itn * 1024);
        a11n = *(const short8v*)(v1p + itn * 1024 + 512);
        if (!hi) aqn = *(const short8v*)(qp + (size_t)(itn * 32 + l31) * 8);

        // ---- scores: 32n x 32m in one MFMA (K=16, 8 real c)
        f32x16 s = __builtin_amdgcn_mfma_f32_32x32x16_bf16(aq, bk, zero16, 0, 0, 0);

        // ---- exp + column-partial sum (lane owns column m0+l31)
        float p[16];
        #pragma unroll
        for (int j = 0; j < 16; ++j) p[j] = __expf(s[j]);
        #pragma unroll
        for (int j = 0; j < 16; ++j) Lacc += p[j];

        // ---- pack to bf16 pairs (rows 2t,2t+1 per word)
        unsigned x0, x1, x2, x3, x4, x5, x6, x7;
        asm("v_cvt_pk_bf16_f32 %0, %1, %2" : "=v"(x0) : "v"(p[0]),  "v"(p[1]));
        asm("v_cvt_pk_bf16_f32 %0, %1, %2" : "=v"(x1) : "v"(p[2]),  "v"(p[3]));
        asm("v_cvt_pk_bf16_f32 %0, %1, %2" : "=v"(x2) : "v"(p[4]),  "v"(p[5]));
        asm("v_cvt_pk_bf16_f32 %0, %1, %2" : "=v"(x3) : "v"(p[6]),  "v"(p[7]));
        asm("v_cvt_pk_bf16_f32 %0, %1, %2" : "=v"(x4) : "v"(p[8]),  "v"(p[9]));
        asm("v_cvt_pk_bf16_f32 %0, %1, %2" : "=v"(x5) : "v"(p[10]), "v"(p[11]));
        asm("v_cvt_pk_bf16_f32 %0, %1, %2" : "=v"(x6) : "v"(p[12]), "v"(p[13]));
        asm("v_cvt_pk_bf16_f32 %0, %1, %2" : "=v"(x7) : "v"(p[14]), "v"(p[15]));

        // ---- D->B transpose entirely in registers (halves exchange)
        asm("v_permlane32_swap_b32 %0, %1" : "+v"(x2), "+v"(x0));
        asm("v_permlane32_swap_b32 %0, %1" : "+v"(x3), "+v"(x1));
        asm("v_permlane32_swap_b32 %0, %1" : "+v"(x6), "+v"(x4));
        asm("v_permlane32_swap_b32 %0, %1" : "+v"(x7), "+v"(x5));

        union { unsigned u[4]; short8v v; } bp0, bp1;
        bp0.u[0] = x0; bp0.u[1] = x1; bp0.u[2] = x2; bp0.u[3] = x3;  // P rows 0..15
        bp1.u[0] = x4; bp1.u[1] = x5; bp1.u[2] = x6; bp1.u[3] = x7;  // P rows 16..31

        // ---- PV: O[c][m] += V[c][n] * P[n][m]   (c tiles 0..31, 32..63)
        acc0 = __builtin_amdgcn_mfma_f32_32x32x16_bf16(a00, bp0.v, acc0, 0, 0, 0);
        acc0 = __builtin_amdgcn_mfma_f32_32x32x16_bf16(a01, bp1.v, acc0, 0, 0, 0);
        acc1 = __builtin_amdgcn_mfma_f32_32x32x16_bf16(a10, bp0.v, acc1, 0, 0, 0);
        acc1 = __builtin_amdgcn_mfma_f32_32x32x16_bf16(a11, bp1.v, acc1, 0, 0, 0);
    }

    // ---- per-wave column sums: lanes l and l+32 cover all 32 rows of col l31
    Lacc += __shfl_xor(Lacc, 32, 64);
    if (lane < 32) Lred[w][l31] = Lacc;

    // ---- O reduction: waves 0-3 write their partial, waves 4-7 RMW-add
    if (w < 4) {
        #pragma unroll
        for (int r = 0; r < 16; ++r) {
            int c = (r & 3) + 8 * (r >> 2) + 4 * hi;
            Ored[w][c][l31]      = acc0[r];
            Ored[w][c + 32][l31] = acc1[r];
        }
    }
    __syncthreads();
    if (w >= 4) {
        #pragma unroll
        for (int r = 0; r < 16; ++r) {
            int c = (r & 3) + 8 * (r >> 2) + 4 * hi;
            Ored[w - 4][c][l31]      += acc0[r];
            Ored[w - 4][c + 32][l31] += acc1[r];
        }
    }
    if (t < 32) {
        float sum = Lred[0][t] + Lred[1][t] + Lred[2][t] + Lred[3][t]
                  + Lred[4][t] + Lred[5][t] + Lred[6][t] + Lred[7][t];
        Lf[t] = 1.f / sum;
    }
    __syncthreads();

    // ---- vectorized epilogue: thread -> (c = t>>3, 4 consecutive m)
    {
        const float gv = gamma[0];
        int c = t >> 3, m4 = (t & 7) * 4;
        float4 o = {0.f, 0.f, 0.f, 0.f};
        #pragma unroll
        for (int k2 = 0; k2 < 4; ++k2) {
            float4 v = *(const float4*)&Ored[k2][c][m4];
            o.x += v.x; o.y += v.y; o.z += v.z; o.w += v.w;
        }
        float4 lf = *(const float4*)&Lf[m4];
        size_t gbase = ((size_t)b * 64 + c) * NN + m0 + m4;
        float4 xv = *(const float4*)&x[gbase];
        float4 r;
        r.x = gv * o.x * lf.x + xv.x;
        r.y = gv * o.y * lf.y + xv.y;
        r.z = gv * o.z * lf.z + xv.z;
        r.w = gv * o.w * lf.w + xv.w;
        *(float4*)&out[gbase] = r;
    }
}

extern "C" void kernel_launch(void* const* d_in, const int* in_sizes, int n_in,
                              void* d_out, int out_size, void* d_ws, size_t ws_size,
                              hipStream_t stream) {
    const float* x     = (const float*)d_in[0];
    const float* Wq    = (const float*)d_in[1];
    const float* Wk    = (const float*)d_in[2];
    const float* Wv    = (const float*)d_in[3];
    const float* gamma = (const float*)d_in[4];
    float* out = (float*)d_out;

    unsigned short* ws = (unsigned short*)d_ws;
    unsigned short* Qt  = ws;                        // [B][N][8]  bf16, 256 KB
    unsigned short* Kt  = Qt + (size_t)BB * NN * 8;  // [B][N][8]  bf16, 256 KB
    unsigned short* Vsw = Kt + (size_t)BB * NN * 8;  // [B][2][256][512] bf16, 2 MB

    qkv_kernel<<<dim3(NN / 64, BB), 256, 0, stream>>>(x, Wq, Wk, Wv, Qt, Kt, Vsw);
    attn_kernel<<<dim3(NN / 32, BB), 512, 0, stream>>>(Qt, Kt, Vsw, x, gamma, out);
}

// Round 2
// 85.072 us; speedup vs baseline: 1.1367x; 1.0157x over previous
//
#include <hip/hip_runtime.h>

#define BB 4
#define NN 4096

typedef __attribute__((ext_vector_type(8))) short short8v;   // 8 bf16 = 4 VGPRs
typedef __attribute__((ext_vector_type(4))) short short4v;   // 4 bf16 = 2 VGPRs
typedef __attribute__((ext_vector_type(4))) float float4v;
typedef __attribute__((ext_vector_type(16))) float f32x16;   // 32x32 MFMA acc

__device__ __forceinline__ unsigned short f2bf_rn(float f) {
    unsigned u = __float_as_uint(f);
    u += 0x7FFFu + ((u >> 16) & 1u);          // round-to-nearest-even
    return (unsigned short)(u >> 16);
}

// ---------------------------------------------------------------------------
// Kernel 1: fused QKV projection as an MFMA GEMM.
// Wq is pre-scaled by log2(e) so the attention loop can use raw v_exp_f32
// (exp2) instead of mul+exp per score element.
// Outputs:
//   Qt[b][n][8], Kt[b][n][8]  (contiguous 16B rows)
//   Vsw: V pre-swizzled into 32x32x16 MFMA A-fragment order: 1 KB chunk per
//   (b, ct in [0,2), ns = n/16): elem[l*8+j] = V[b][ct*32+(l&31)][ns*16+(l>>5)*8+j]
// ---------------------------------------------------------------------------
__global__ __launch_bounds__(256) void qkv_kernel(
    const float* __restrict__ x,
    const float* __restrict__ Wq, const float* __restrict__ Wk,
    const float* __restrict__ Wv,
    unsigned short* __restrict__ Qt, unsigned short* __restrict__ Kt,
    unsigned short* __restrict__ Vsw)
{
    __shared__ __align__(16) unsigned short xs[64][68];   // [c][n] bf16
    __shared__ __align__(16) unsigned short Ot[64][72];   // [c][n] V staging (144B rows)

    const int t    = threadIdx.x;
    const int w    = t >> 6;
    const int lane = t & 63;
    const int quad = lane >> 4;
    const int l15  = lane & 15;
    const int b    = blockIdx.y;
    const int n0   = blockIdx.x * 64;

    // ---- stage x tile (fp32 -> bf16)
    #pragma unroll
    for (int i = 0; i < 4; ++i) {
        int c  = (t >> 4) + i * 16;
        int n4 = (t & 15) * 4;
        float4 xv = *(const float4*)&x[(size_t)(b * 64 + c) * NN + n0 + n4];
        short4v pk;
        pk[0] = (short)f2bf_rn(xv.x); pk[1] = (short)f2bf_rn(xv.y);
        pk[2] = (short)f2bf_rn(xv.z); pk[3] = (short)f2bf_rn(xv.w);
        *(short4v*)&xs[c][n4] = pk;
    }

    // ---- W B-fragments: B[k=c][o=l15]   (Wq rows scaled by log2 e)
    short8v bw[5][2];
    #pragma unroll
    for (int ot = 0; ot < 5; ++ot) {
        int o = ot * 16 + l15;
        const float* base = (o < 8)  ? (Wq + o * 64)
                           : (o < 16) ? (Wk + (o - 8) * 64)
                                      : (Wv + (o - 16) * 64);
        const float scale = (o < 8) ? 1.4426950408889634f : 1.0f;
        #pragma unroll
        for (int h = 0; h < 2; ++h) {
            float4 u0 = *(const float4*)&base[h * 32 + quad * 8];
            float4 u1 = *(const float4*)&base[h * 32 + quad * 8 + 4];
            short8v f;
            f[0] = (short)f2bf_rn(u0.x * scale); f[1] = (short)f2bf_rn(u0.y * scale);
            f[2] = (short)f2bf_rn(u0.z * scale); f[3] = (short)f2bf_rn(u0.w * scale);
            f[4] = (short)f2bf_rn(u1.x * scale); f[5] = (short)f2bf_rn(u1.y * scale);
            f[6] = (short)f2bf_rn(u1.z * scale); f[7] = (short)f2bf_rn(u1.w * scale);
            bw[ot][h] = f;
        }
    }
    __syncthreads();

    // ---- A-fragments: A[m=n][k=c] from xs
    short8v a0, a1;
    {
        unsigned short* p0 = (unsigned short*)&a0;
        unsigned short* p1 = (unsigned short*)&a1;
        const int nn = w * 16 + l15;
        #pragma unroll
        for (int j = 0; j < 8; ++j) {
            p0[j] = xs[quad * 8 + j][nn];
            p1[j] = xs[32 + quad * 8 + j][nn];
        }
    }

    const float4v zacc = {0.f, 0.f, 0.f, 0.f};
    #pragma unroll
    for (int ot = 0; ot < 5; ++ot) {
        float4v d = __builtin_amdgcn_mfma_f32_16x16x32_bf16(a0, bw[ot][0], zacc, 0, 0, 0);
        d = __builtin_amdgcn_mfma_f32_16x16x32_bf16(a1, bw[ot][1], d, 0, 0, 0);
        if (ot == 0) {
            #pragma unroll
            for (int r = 0; r < 4; ++r) {
                unsigned short v = f2bf_rn(d[r]);
                size_t n = (size_t)(n0 + w * 16 + quad * 4 + r);
                if (l15 < 8) Qt[((size_t)b * NN + n) * 8 + l15] = v;
                else         Kt[((size_t)b * NN + n) * 8 + (l15 - 8)] = v;
            }
        } else {
            short4v pk;
            #pragma unroll
            for (int r = 0; r < 4; ++r) pk[r] = (short)f2bf_rn(d[r]);
            *(short4v*)&Ot[(ot - 1) * 16 + l15][w * 16 + quad * 4] = pk;
        }
    }
    __syncthreads();

    // ---- swizzled V writer for 32x32x16 A-fragments (1 KB coalesced chunks)
    #pragma unroll
    for (int h = 0; h < 2; ++h) {
        int ci  = w * 2 + h;
        int ct  = ci >> 2, nsl = ci & 3;
        short8v d = *(const short8v*)&Ot[ct * 32 + (lane & 31)][nsl * 16 + ((lane >> 5) << 3)];
        size_t ns = (size_t)blockIdx.x * 4 + nsl;
        unsigned short* cb = Vsw + (((size_t)b * 2 + ct) * 256 + ns) * 512;
        *(short8v*)(cb + lane * 8) = d;
    }
}

// ---------------------------------------------------------------------------
// Kernel 2: streaming attention, 32x32x16 MFMA, fully in-register softmax.
// Block = 8 waves (512 thr); block owns (b, 32-wide m-tile). Wave w owns
// n in [w*512, (w+1)*512), 16 iters of 32 n. Zero LDS in the main loop.
// Register diet vs r1: no p[16] (exp fused into cvt_pk), V single-buffered
// (loads at iter top, consumed by PV at iter bottom), only Q prefetched.
// Live VGPRs ~102 -> fits the 128 cap of (512,4) without scratch spill.
// ---------------------------------------------------------------------------
__global__ __launch_bounds__(512, 4) void attn_kernel(
    const unsigned short* __restrict__ Qt,
    const unsigned short* __restrict__ Kt,
    const unsigned short* __restrict__ Vsw,
    const float* __restrict__ x, const float* __restrict__ gamma,
    float* __restrict__ out)
{
    __shared__ __align__(16) float Ored[4][64][36];   // 36.9 KB
    __shared__ __align__(16) float Lred[8][32];
    __shared__ __align__(16) float Lf[32];

    const int t    = threadIdx.x;
    const int w    = t >> 6;
    const int lane = t & 63;
    const int hi   = lane >> 5;
    const int l31  = lane & 31;
    const int b    = blockIdx.y;
    const int m0   = blockIdx.x * 32;

    const short8v zfrag = {0, 0, 0, 0, 0, 0, 0, 0};
    const f32x16 zero16 = {0.f, 0.f, 0.f, 0.f, 0.f, 0.f, 0.f, 0.f,
                           0.f, 0.f, 0.f, 0.f, 0.f, 0.f, 0.f, 0.f};

    // K-side (query-column) B fragment: k=c=(hi*8+j); only c<8 real -> lo half
    short8v bk = zfrag;
    if (!hi) bk = *(const short8v*)(Kt + ((size_t)b * NN + m0 + l31) * 8);

    f32x16 acc0 = zero16, acc1 = zero16;
    float La = 0.f, Lb = 0.f;

    const unsigned short* qp  = Qt + ((size_t)b * NN + w * 512) * 8;
    const unsigned short* v0p = Vsw + ((size_t)b * 2 * 256 + w * 32) * 512 + lane * 8;
    const unsigned short* v1p = v0p + 256 * 512;

    // ---- prefetch Q for iter 0
    short8v aqn = zfrag;
    if (!hi) aqn = *(const short8v*)(qp + (size_t)l31 * 8);

    for (int it = 0; it < 16; ++it) {
        // V loads for THIS iter: issued now, consumed by PV ~300 issue-cycles
        // later (QK + exp + pack in between) -> latency hidden + 4-wave TLP.
        short8v a00 = *(const short8v*)(v0p + it * 1024);
        short8v a01 = *(const short8v*)(v0p + it * 1024 + 512);
        short8v a10 = *(const short8v*)(v1p + it * 1024);
        short8v a11 = *(const short8v*)(v1p + it * 1024 + 512);

        short8v aq = aqn;

        // ---- scores: 32n x 32m in one MFMA (K=16, 8 real c); pre-scaled by log2 e
        f32x16 s = __builtin_amdgcn_mfma_f32_32x32x16_bf16(aq, bk, zero16, 0, 0, 0);

        // prefetch next iteration's Q (wrap -> harmless re-read of 0)
        const int itn = (it + 1) & 15;
        if (!hi) aqn = *(const short8v*)(qp + (size_t)(itn * 32 + l31) * 8);

        // ---- fused exp2 + column-partial sums + bf16 pack (rows 2t,2t+1/word)
        unsigned xw[8];
        #pragma unroll
        for (int j = 0; j < 8; ++j) {
            float e0 = __builtin_amdgcn_exp2f(s[2 * j]);
            float e1 = __builtin_amdgcn_exp2f(s[2 * j + 1]);
            La += e0;
            Lb += e1;
            asm("v_cvt_pk_bf16_f32 %0, %1, %2" : "=v"(xw[j]) : "v"(e0), "v"(e1));
        }

        // ---- D->B transpose entirely in registers (halves exchange)
        asm("v_permlane32_swap_b32 %0, %1" : "+v"(xw[2]), "+v"(xw[0]));
        asm("v_permlane32_swap_b32 %0, %1" : "+v"(xw[3]), "+v"(xw[1]));
        asm("v_permlane32_swap_b32 %0, %1" : "+v"(xw[6]), "+v"(xw[4]));
        asm("v_permlane32_swap_b32 %0, %1" : "+v"(xw[7]), "+v"(xw[5]));

        union { unsigned u[4]; short8v v; } bp0, bp1;
        bp0.u[0] = xw[0]; bp0.u[1] = xw[1]; bp0.u[2] = xw[2]; bp0.u[3] = xw[3];
        bp1.u[0] = xw[4]; bp1.u[1] = xw[5]; bp1.u[2] = xw[6]; bp1.u[3] = xw[7];

        // ---- PV: O[c][m] += V[c][n] * P[n][m]   (c tiles 0..31, 32..63)
        __builtin_amdgcn_s_setprio(1);
        acc0 = __builtin_amdgcn_mfma_f32_32x32x16_bf16(a00, bp0.v, acc0, 0, 0, 0);
        acc0 = __builtin_amdgcn_mfma_f32_32x32x16_bf16(a01, bp1.v, acc0, 0, 0, 0);
        acc1 = __builtin_amdgcn_mfma_f32_32x32x16_bf16(a10, bp0.v, acc1, 0, 0, 0);
        acc1 = __builtin_amdgcn_mfma_f32_32x32x16_bf16(a11, bp1.v, acc1, 0, 0, 0);
        __builtin_amdgcn_s_setprio(0);
    }

    float Lacc = La + Lb;

    // ---- per-wave column sums: lanes l and l+32 cover all 32 rows of col l31
    Lacc += __shfl_xor(Lacc, 32, 64);
    if (lane < 32) Lred[w][l31] = Lacc;

    // ---- O reduction: waves 0-3 write their partial, waves 4-7 RMW-add
    if (w < 4) {
        #pragma unroll
        for (int r = 0; r < 16; ++r) {
            int c = (r & 3) + 8 * (r >> 2) + 4 * hi;
            Ored[w][c][l31]      = acc0[r];
            Ored[w][c + 32][l31] = acc1[r];
        }
    }
    __syncthreads();
    if (w >= 4) {
        #pragma unroll
        for (int r = 0; r < 16; ++r) {
            int c = (r & 3) + 8 * (r >> 2) + 4 * hi;
            Ored[w - 4][c][l31]      += acc0[r];
            Ored[w - 4][c + 32][l31] += acc1[r];
        }
    }
    if (t < 32) {
        float sum = Lred[0][t] + Lred[1][t] + Lred[2][t] + Lred[3][t]
                  + Lred[4][t] + Lred[5][t] + Lred[6][t] + Lred[7][t];
        Lf[t] = 1.f / sum;
    }
    __syncthreads();

    // ---- vectorized epilogue: thread -> (c = t>>3, 4 consecutive m)
    {
        const float gv = gamma[0];
        int c = t >> 3, m4 = (t & 7) * 4;
        float4 o = {0.f, 0.f, 0.f, 0.f};
        #pragma unroll
        for (int k2 = 0; k2 < 4; ++k2) {
            float4 v = *(const float4*)&Ored[k2][c][m4];
            o.x += v.x; o.y += v.y; o.z += v.z; o.w += v.w;
        }
        float4 lf = *(const float4*)&Lf[m4];
        size_t gbase = ((size_t)b * 64 + c) * NN + m0 + m4;
        float4 xv = *(const float4*)&x[gbase];
        float4 r;
        r.x = gv * o.x * lf.x + xv.x;
        r.y = gv * o.y * lf.y + xv.y;
        r.z = gv * o.z * lf.z + xv.z;
        r.w = gv * o.w * lf.w + xv.w;
        *(float4*)&out[gbase] = r;
    }
}

extern "C" void kernel_launch(void* const* d_in, const int* in_sizes, int n_in,
                              void* d_out, int out_size, void* d_ws, size_t ws_size,
                              hipStream_t stream) {
    const float* x     = (const float*)d_in[0];
    const float* Wq    = (const float*)d_in[1];
    const float* Wk    = (const float*)d_in[2];
    const float* Wv    = (const float*)d_in[3];
    const float* gamma = (const float*)d_in[4];
    float* out = (float*)d_out;

    unsigned short* ws = (unsigned short*)d_ws;
    unsigned short* Qt  = ws;                        // [B][N][8]  bf16, 256 KB
    unsigned short* Kt  = Qt + (size_t)BB * NN * 8;  // [B][N][8]  bf16, 256 KB
    unsigned short* Vsw = Kt + (size_t)BB * NN * 8;  // [B][2][256][512] bf16, 2 MB

    qkv_kernel<<<dim3(NN / 64, BB), 256, 0, stream>>>(x, Wq, Wk, Wv, Qt, Kt, Vsw);
    attn_kernel<<<dim3(NN / 32, BB), 512, 0, stream>>>(Qt, Kt, Vsw, x, gamma, out);
}